// Round 10
// baseline (278.384 us; speedup 1.0000x reference)
//
#include <hip/hip_runtime.h>
#include <hip/hip_bf16.h>
#include <cstdint>

#define B_ 2
#define T_ 2048
#define D_ 2048
#define H_ 32
#define KVH_ 8
#define HD_ 64
#define NQKV_ 3072
#define M_ 4096

typedef __attribute__((ext_vector_type(8))) __bf16 bf16x8;
typedef __attribute__((ext_vector_type(4))) float f32x4;
typedef __attribute__((ext_vector_type(4))) uint32_t u32x4;

__device__ __forceinline__ uint16_t f2bf(float f) {
  uint32_t u = __builtin_bit_cast(uint32_t, f);
  return (uint16_t)((u + 0x7FFFu + ((u >> 16) & 1u)) >> 16);
}

__device__ __forceinline__ uint32_t cvt_pk(float lo, float hi) {
  uint32_t r;
  asm("v_cvt_pk_bf16_f32 %0, %1, %2" : "=v"(r) : "v"(lo), "v"(hi));
  return r;
}

__device__ __forceinline__ void gload_lds16(const void* g, void* l) {
  __builtin_amdgcn_global_load_lds(
      (const __attribute__((address_space(1))) void*)(uintptr_t)g,
      (__attribute__((address_space(3))) void*)(uintptr_t)l, 16, 0, 0);
}

// ---------------- fp32 -> bf16 convert (vectorized x8) ----------------
__global__ void cvt_bf16_k(const float* __restrict__ in, uint16_t* __restrict__ out, int n) {
  int i = (blockIdx.x * 256 + threadIdx.x) * 8;
  if (i >= n) return;
  float4 a = *reinterpret_cast<const float4*>(in + i);
  float4 b = *reinterpret_cast<const float4*>(in + i + 4);
  uint4 v;
  v.x = (uint32_t)f2bf(a.x) | ((uint32_t)f2bf(a.y) << 16);
  v.y = (uint32_t)f2bf(a.z) | ((uint32_t)f2bf(a.w) << 16);
  v.z = (uint32_t)f2bf(b.x) | ((uint32_t)f2bf(b.y) << 16);
  v.w = (uint32_t)f2bf(b.z) | ((uint32_t)f2bf(b.w) << 16);
  *reinterpret_cast<uint4*>(out + i) = v;
}

__global__ void concat_bias_k(const float* __restrict__ bq, const float* __restrict__ bk,
                              const float* __restrict__ bv, float* __restrict__ out) {
  int i = blockIdx.x * 256 + threadIdx.x;
  if (i >= NQKV_) return;
  out[i] = (i < D_) ? bq[i] : (i < D_ + 512) ? bk[i - D_] : bv[i - D_ - 512];
}

__global__ void rope_tab_k(float* __restrict__ cosT, float* __restrict__ sinT) {
  int i = blockIdx.x * 256 + threadIdx.x;  // 2048*32
  int d = i & 31;
  int t = i >> 5;
  float inv = expf(-(float)d * (1.0f / 32.0f) * logf(10000.0f));
  float f = (float)t * inv;
  cosT[i] = cosf(f);
  sinT[i] = sinf(f);
}

// ---------------- GEMM: C[m][n] = sum_k A[m][k]*Bw[n][k] + bias[n] ----------------
// XCD-aware swizzle (T1): contiguous tile chunks per XCD for L2 panel reuse.
#define BM 128
#define BN 128
#define BK 64
__global__ __launch_bounds__(256, 2)
void gemm_bf16(const uint16_t* __restrict__ A, const uint16_t* __restrict__ Bw,
               const float* __restrict__ bias, float* __restrict__ C,
               int M, int N, int K) {
  __shared__ __align__(16) uint16_t As[BM * BK];
  __shared__ __align__(16) uint16_t Bs[BN * BK];
  const int tid = threadIdx.x;
  const int lane = tid & 63;
  const int w = tid >> 6;
  const int wm = w >> 1, wn = w & 1;
  const int l16 = lane & 15, lq = lane >> 4;

  int lin = blockIdx.y * gridDim.x + blockIdx.x;
  int qn = (gridDim.x * gridDim.y) >> 3;   // nwg % 8 == 0 for both calls
  int swz = (lin & 7) * qn + (lin >> 3);
  const int m0 = (swz / gridDim.x) * BM, n0 = (swz % gridDim.x) * BN;

  f32x4 acc[4][4] = {};

  for (int k0 = 0; k0 < K; k0 += BK) {
#pragma unroll
    for (int r = 0; r < 4; ++r) {
      int idx = r * 256 + tid;
      int row = idx >> 3;
      int c8 = (idx & 7) ^ (row & 7);
      gload_lds16(A + (size_t)(m0 + row) * K + k0 + c8 * 8, &As[idx * 8]);
    }
#pragma unroll
    for (int r = 0; r < 4; ++r) {
      int idx = r * 256 + tid;
      int row = idx >> 3;
      int c8 = (idx & 7) ^ (row & 7);
      gload_lds16(Bw + (size_t)(n0 + row) * K + k0 + c8 * 8, &Bs[idx * 8]);
    }
    __syncthreads();
#pragma unroll
    for (int ks = 0; ks < 2; ++ks) {
      bf16x8 av[4], bv[4];
      int k8 = ks * 4 + lq;
#pragma unroll
      for (int mi = 0; mi < 4; ++mi) {
        int row = wm * 64 + mi * 16 + l16;
        av[mi] = *reinterpret_cast<const bf16x8*>(&As[row * BK + ((k8 ^ (row & 7)) * 8)]);
      }
#pragma unroll
      for (int ni = 0; ni < 4; ++ni) {
        int row = wn * 64 + ni * 16 + l16;
        bv[ni] = *reinterpret_cast<const bf16x8*>(&Bs[row * BK + ((k8 ^ (row & 7)) * 8)]);
      }
#pragma unroll
      for (int mi = 0; mi < 4; ++mi)
#pragma unroll
        for (int ni = 0; ni < 4; ++ni)
          acc[mi][ni] = __builtin_amdgcn_mfma_f32_16x16x32_bf16(av[mi], bv[ni], acc[mi][ni], 0, 0, 0);
    }
    __syncthreads();
  }

#pragma unroll
  for (int mi = 0; mi < 4; ++mi) {
    int r0 = m0 + wm * 64 + mi * 16 + lq * 4;
#pragma unroll
    for (int ni = 0; ni < 4; ++ni) {
      int c = n0 + wn * 64 + ni * 16 + l16;
      float bb = bias[c];
#pragma unroll
      for (int rr = 0; rr < 4; ++rr)
        C[(size_t)(r0 + rr) * N + c] = acc[mi][ni][rr] + bb;
    }
  }
}

// ---------------- RoPE on Q,K + pack to bf16 head-major layouts ----------------
// Q is pre-scaled by 0.125*log2(e): folds the softmax scale + exp2 domain into
// the Q operand so the flash kernel's QK^T output is directly the exp2 input.
__global__ void rope_qk_k(const float* __restrict__ QKV, const float* __restrict__ cosT,
                          const float* __restrict__ sinT, uint16_t* __restrict__ qb,
                          uint16_t* __restrict__ kb) {
  int tid = blockIdx.x * 256 + threadIdx.x;  // B*40*T*32
  int d = tid & 31;
  int t = (tid >> 5) & (T_ - 1);
  int rest = tid >> 16;
  int hh = rest % 40;
  int b = rest / 40;
  const float PREQ = 0.125f * 1.44269504f;
  float c = cosT[t * 32 + d];
  float s = sinT[t * 32 + d];
  size_t rowoff = (size_t)(b * T_ + t) * NQKV_;
  if (hh < H_) {
    const float* q = QKV + rowoff + hh * 64;
    float x1 = q[d], x2 = q[d + 32];
    size_t ov = ((size_t)(b * H_ + hh) * T_ + t) * 64;
    qb[ov + d] = f2bf((x1 * c - x2 * s) * PREQ);
    qb[ov + d + 32] = f2bf((x2 * c + x1 * s) * PREQ);
  } else {
    int kh = hh - H_;
    const float* kp = QKV + rowoff + D_ + kh * 64;
    float x1 = kp[d], x2 = kp[d + 32];
    size_t ov = ((size_t)(b * KVH_ + kh) * T_ + t) * 64;
    kb[ov + d] = f2bf(x1 * c - x2 * s);
    kb[ov + d + 32] = f2bf(x2 * c + x1 * s);
  }
}

// ---------------- V -> transposed bf16 [B][KVH][64][T] ----------------
__global__ void cvt_v_k(const float* __restrict__ QKV, uint16_t* __restrict__ vt) {
  int tid = blockIdx.x * 256 + threadIdx.x;
  int t8 = tid & 255;
  int rest = tid >> 8;
  int b = rest >> 9;
  int col = 2560 + (rest & 511);
  uint16_t tmp[8];
#pragma unroll
  for (int i = 0; i < 8; ++i)
    tmp[i] = f2bf(QKV[(size_t)(b * T_ + t8 * 8 + i) * NQKV_ + col]);
  uint4 v;
  v.x = (uint32_t)tmp[0] | ((uint32_t)tmp[1] << 16);
  v.y = (uint32_t)tmp[2] | ((uint32_t)tmp[3] << 16);
  v.z = (uint32_t)tmp[4] | ((uint32_t)tmp[5] << 16);
  v.w = (uint32_t)tmp[6] | ((uint32_t)tmp[7] << 16);
  *reinterpret_cast<uint4*>(vt + (size_t)rest * T_ + t8 * 8) = v;
}

// ---------------- flash attention (causal, GQA), swapped QK^T ----------------
// r9 math (no row-max, l via ones-MFMA) + explicit K double-buffer (T14):
// next iteration's 8 K-loads issue right after current QK^T, hiding L2/L3
// latency under the exp2+LDS+PV section. Named ping-pong buffers (rule #20).
__global__ __launch_bounds__(256, 2)
void flash_attn_k(const uint16_t* __restrict__ qb, const uint16_t* __restrict__ kb,
                  const uint16_t* __restrict__ vt, uint16_t* __restrict__ ob) {
  __shared__ __align__(16) uint16_t P_lds[4][32 * 72];  // per-wave 32 q x 64+pad
  const int lane = threadIdx.x & 63;
  const int w = threadIdx.x >> 6;
  const int l16 = lane & 15, lq = lane >> 4;
  const int bh = (blockIdx.x & 15) * 4 + w;
  const int rank = blockIdx.x >> 4;              // 0..63
  const int pair = rank & 31;
  const int tile = (rank & 32) ? (63 - pair) : pair;
  const int b = bh >> 5, h = bh & 31;
  const int kvh = h >> 2;
  uint16_t* P = P_lds[w];

  const uint16_t* Qp = qb + (size_t)(b * H_ + h) * T_ * HD_;
  const uint16_t* Kp = kb + (size_t)(b * KVH_ + kvh) * T_ * HD_;
  const uint16_t* Vp = vt + (size_t)(b * KVH_ + kvh) * HD_ * T_;

  const int q0 = tile * 32;
  u32x4 ones_u = {0x3F803F80u, 0x3F803F80u, 0x3F803F80u, 0x3F803F80u};
  bf16x8 ones = __builtin_bit_cast(bf16x8, ones_u);

  // Q fragments (B-operand), pre-scaled: Q[q = q0+mf*16+l16][k = ks*32+lq*8 ..]
  bf16x8 aq[2][2];
#pragma unroll
  for (int mf = 0; mf < 2; ++mf)
#pragma unroll
    for (int ks = 0; ks < 2; ++ks)
      aq[mf][ks] = *reinterpret_cast<const bf16x8*>(
          Qp + (size_t)(q0 + mf * 16 + l16) * HD_ + ks * 32 + lq * 8);

  f32x4 acc[2][4] = {};        // O^T: [q-tile mf][d-tile dn]; lane: q=l16, d=lq*4+r
  f32x4 acc_l[2] = {};         // l (unnormalized softmax denom), col = q = l16

  const int nt = (tile >> 1) + 1;

  bf16x8 kA[2][4], kB[2][4];
  // prologue: K tile 0 into A
#pragma unroll
  for (int ks = 0; ks < 2; ++ks)
#pragma unroll
    for (int nf = 0; nf < 4; ++nf)
      kA[ks][nf] = *reinterpret_cast<const bf16x8*>(
          Kp + (size_t)(nf * 16 + l16) * HD_ + ks * 32 + lq * 8);

#define FLASH_STEP(KCUR, KNXT, IT)                                                     \
  do {                                                                                 \
    const int kv0 = (IT) * 64;                                                         \
    f32x4 sacc[4][2] = {};                                                             \
    _Pragma("unroll")                                                                  \
    for (int ks = 0; ks < 2; ++ks)                                                     \
      _Pragma("unroll")                                                                \
      for (int nf = 0; nf < 4; ++nf)                                                   \
        _Pragma("unroll")                                                              \
        for (int mf = 0; mf < 2; ++mf)                                                 \
          sacc[nf][mf] = __builtin_amdgcn_mfma_f32_16x16x32_bf16(                      \
              KCUR[ks][nf], aq[mf][ks], sacc[nf][mf], 0, 0, 0);                        \
    const int kvn = ((IT) + 1 < nt) ? kv0 + 64 : kv0;                                  \
    _Pragma("unroll")                                                                  \
    for (int ks = 0; ks < 2; ++ks)                                                     \
      _Pragma("unroll")                                                                \
      for (int nf = 0; nf < 4; ++nf)                                                   \
        KNXT[ks][nf] = *reinterpret_cast<const bf16x8*>(                               \
            Kp + (size_t)(kvn + nf * 16 + l16) * HD_ + ks * 32 + lq * 8);              \
    bf16x8 vv[2][4];                                                                   \
    _Pragma("unroll")                                                                  \
    for (int k2 = 0; k2 < 2; ++k2)                                                     \
      _Pragma("unroll")                                                                \
      for (int dn = 0; dn < 4; ++dn)                                                   \
        vv[k2][dn] = *reinterpret_cast<const bf16x8*>(                                 \
            Vp + (size_t)(dn * 16 + l16) * T_ + kv0 + k2 * 32 + lq * 8);               \
    if ((IT) == nt - 1) {                                                              \
      _Pragma("unroll")                                                                \
      for (int mf = 0; mf < 2; ++mf) {                                                 \
        int qg = q0 + mf * 16 + l16;                                                   \
        _Pragma("unroll")                                                              \
        for (int nf = 0; nf < 4; ++nf)                                                 \
          _Pragma("unroll")                                                            \
          for (int r = 0; r < 4; ++r)                                                  \
            if (kv0 + nf * 16 + lq * 4 + r > qg) sacc[nf][mf][r] = -1e30f;             \
      }                                                                                \
    }                                                                                  \
    _Pragma("unroll")                                                                  \
    for (int mf = 0; mf < 2; ++mf) {                                                   \
      uint16_t* rowp = P + (mf * 16 + l16) * 72;                                       \
      _Pragma("unroll")                                                                \
      for (int nf = 0; nf < 4; ++nf) {                                                 \
        float p0 = __builtin_amdgcn_exp2f(sacc[nf][mf][0]);                            \
        float p1 = __builtin_amdgcn_exp2f(sacc[nf][mf][1]);                            \
        float p2 = __builtin_amdgcn_exp2f(sacc[nf][mf][2]);                            \
        float p3 = __builtin_amdgcn_exp2f(sacc[nf][mf][3]);                            \
        uint2 pk;                                                                      \
        pk.x = cvt_pk(p0, p1);                                                         \
        pk.y = cvt_pk(p2, p3);                                                         \
        *reinterpret_cast<uint2*>(rowp + nf * 16 + lq * 4) = pk;                       \
      }                                                                                \
    }                                                                                  \
    bf16x8 pa[2][2];                                                                   \
    _Pragma("unroll")                                                                  \
    for (int mf = 0; mf < 2; ++mf)                                                     \
      _Pragma("unroll")                                                                \
      for (int k2 = 0; k2 < 2; ++k2)                                                   \
        pa[mf][k2] = *reinterpret_cast<const bf16x8*>(                                 \
            P + (mf * 16 + l16) * 72 + k2 * 32 + lq * 8);                              \
    _Pragma("unroll")                                                                  \
    for (int k2 = 0; k2 < 2; ++k2)                                                     \
      _Pragma("unroll")                                                                \
      for (int mf = 0; mf < 2; ++mf) {                                                 \
        acc_l[mf] = __builtin_amdgcn_mfma_f32_16x16x32_bf16(ones, pa[mf][k2],          \
                                                            acc_l[mf], 0, 0, 0);      \
        _Pragma("unroll")                                                              \
        for (int dn = 0; dn < 4; ++dn)                                                 \
          acc[mf][dn] = __builtin_amdgcn_mfma_f32_16x16x32_bf16(                       \
              vv[k2][dn], pa[mf][k2], acc[mf][dn], 0, 0, 0);                           \
      }                                                                                \
  } while (0)

  {
    int it = 0;
    for (;;) {
      FLASH_STEP(kA, kB, it);
      ++it;
      if (it == nt) break;
      FLASH_STEP(kB, kA, it);
      ++it;
      if (it == nt) break;
    }
  }
#undef FLASH_STEP

  // epilogue: normalize, transpose O^T -> O through LDS, coalesced store
#pragma unroll
  for (int mf = 0; mf < 2; ++mf) {
    float inv = 1.0f / acc_l[mf][0];
    uint16_t* rowp = P + (mf * 16 + l16) * 72;
#pragma unroll
    for (int dn = 0; dn < 4; ++dn) {
      uint2 pk;
      pk.x = cvt_pk(acc[mf][dn][0] * inv, acc[mf][dn][1] * inv);
      pk.y = cvt_pk(acc[mf][dn][2] * inv, acc[mf][dn][3] * inv);
      *reinterpret_cast<uint2*>(rowp + dn * 16 + lq * 4) = pk;
    }
  }
  {
    int orow = lane >> 1, ohalf = (lane & 1) * 32;
    uint16_t* op = ob + (size_t)(b * T_ + q0 + orow) * D_ + h * HD_ + ohalf;
    const uint16_t* lp = P + orow * 72 + ohalf;
#pragma unroll
    for (int j = 0; j < 4; ++j)
      *reinterpret_cast<uint4*>(op + j * 8) = *reinterpret_cast<const uint4*>(lp + j * 8);
  }
}

extern "C" void kernel_launch(void* const* d_in, const int* in_sizes, int n_in,
                              void* d_out, int out_size, void* d_ws, size_t ws_size,
                              hipStream_t stream) {
  const float* x  = (const float*)d_in[0];
  const float* Wq = (const float*)d_in[1];
  const float* bq = (const float*)d_in[2];
  const float* Wk = (const float*)d_in[3];
  const float* bk = (const float*)d_in[4];
  const float* Wv = (const float*)d_in[5];
  const float* bv = (const float*)d_in[6];
  const float* Wo = (const float*)d_in[7];
  const float* bo = (const float*)d_in[8];
  float* out = (float*)d_out;

  char* ws = (char*)d_ws;
  size_t off = 0;
  auto alloc = [&](size_t bytes) {
    void* p = ws + off;
    off += (bytes + 255) & ~(size_t)255;
    return p;
  };
  uint16_t* xb    = (uint16_t*)alloc((size_t)M_ * D_ * 2);
  uint16_t* wqkv  = (uint16_t*)alloc((size_t)NQKV_ * D_ * 2);
  uint16_t* wo_b  = (uint16_t*)alloc((size_t)D_ * D_ * 2);
  float*    bqkv  = (float*)alloc(NQKV_ * 4);
  float*    cosT  = (float*)alloc(T_ * 32 * 4);
  float*    sinT  = (float*)alloc(T_ * 32 * 4);
  uint16_t* q_bf  = (uint16_t*)alloc((size_t)B_ * H_ * T_ * HD_ * 2);
  uint16_t* k_bf  = (uint16_t*)alloc((size_t)B_ * KVH_ * T_ * HD_ * 2);
  uint16_t* vt_bf = (uint16_t*)alloc((size_t)B_ * KVH_ * T_ * HD_ * 2);
  float*    qkvf  = (float*)alloc((size_t)M_ * NQKV_ * 4);
  uint16_t* attn_bf = (uint16_t*)qkvf;  // reuse: QKV fp32 dead after rope/cvt_v

  cvt_bf16_k<<<4096, 256, 0, stream>>>(x, xb, M_ * D_);
  cvt_bf16_k<<<2048, 256, 0, stream>>>(Wq, wqkv, D_ * D_);
  cvt_bf16_k<<<512, 256, 0, stream>>>(Wk, wqkv + (size_t)D_ * D_, 512 * D_);
  cvt_bf16_k<<<512, 256, 0, stream>>>(Wv, wqkv + (size_t)2560 * D_, 512 * D_);
  cvt_bf16_k<<<2048, 256, 0, stream>>>(Wo, wo_b, D_ * D_);
  concat_bias_k<<<12, 256, 0, stream>>>(bq, bk, bv, bqkv);
  rope_tab_k<<<256, 256, 0, stream>>>(cosT, sinT);

  gemm_bf16<<<dim3(NQKV_ / BN, M_ / BM), 256, 0, stream>>>(xb, wqkv, bqkv, qkvf, M_, NQKV_, D_);

  rope_qk_k<<<(B_ * 40 * T_ * 32) / 256, 256, 0, stream>>>(qkvf, cosT, sinT, q_bf, k_bf);
  cvt_v_k<<<(B_ * KVH_ * HD_ * (T_ / 8)) / 256, 256, 0, stream>>>(qkvf, vt_bf);

  flash_attn_k<<<1024, 256, 0, stream>>>(q_bf, k_bf, vt_bf, attn_bf);

  gemm_bf16<<<dim3(D_ / BN, M_ / BM), 256, 0, stream>>>(attn_bf, wo_b, bo, out, M_, D_, D_);
}

// Round 11
// 206.406 us; speedup vs baseline: 1.3487x; 1.3487x over previous
//
#include <hip/hip_runtime.h>
#include <hip/hip_bf16.h>
#include <cstdint>

#define B_ 2
#define T_ 2048
#define D_ 2048
#define H_ 32
#define KVH_ 8
#define HD_ 64
#define NQKV_ 3072
#define M_ 4096

typedef __attribute__((ext_vector_type(8))) __bf16 bf16x8;
typedef __attribute__((ext_vector_type(4))) float f32x4;
typedef __attribute__((ext_vector_type(4))) uint32_t u32x4;

__device__ __forceinline__ uint16_t f2bf(float f) {
  uint32_t u = __builtin_bit_cast(uint32_t, f);
  return (uint16_t)((u + 0x7FFFu + ((u >> 16) & 1u)) >> 16);
}

__device__ __forceinline__ uint32_t cvt_pk(float lo, float hi) {
  uint32_t r;
  asm("v_cvt_pk_bf16_f32 %0, %1, %2" : "=v"(r) : "v"(lo), "v"(hi));
  return r;
}

__device__ __forceinline__ void gload_lds16(const void* g, void* l) {
  __builtin_amdgcn_global_load_lds(
      (const __attribute__((address_space(1))) void*)(uintptr_t)g,
      (__attribute__((address_space(3))) void*)(uintptr_t)l, 16, 0, 0);
}

// ---------------- fp32 -> bf16 convert (vectorized x8) ----------------
__global__ void cvt_bf16_k(const float* __restrict__ in, uint16_t* __restrict__ out, int n) {
  int i = (blockIdx.x * 256 + threadIdx.x) * 8;
  if (i >= n) return;
  float4 a = *reinterpret_cast<const float4*>(in + i);
  float4 b = *reinterpret_cast<const float4*>(in + i + 4);
  uint4 v;
  v.x = (uint32_t)f2bf(a.x) | ((uint32_t)f2bf(a.y) << 16);
  v.y = (uint32_t)f2bf(a.z) | ((uint32_t)f2bf(a.w) << 16);
  v.z = (uint32_t)f2bf(b.x) | ((uint32_t)f2bf(b.y) << 16);
  v.w = (uint32_t)f2bf(b.z) | ((uint32_t)f2bf(b.w) << 16);
  *reinterpret_cast<uint4*>(out + i) = v;
}

__global__ void concat_bias_k(const float* __restrict__ bq, const float* __restrict__ bk,
                              const float* __restrict__ bv, float* __restrict__ out) {
  int i = blockIdx.x * 256 + threadIdx.x;
  if (i >= NQKV_) return;
  out[i] = (i < D_) ? bq[i] : (i < D_ + 512) ? bk[i - D_] : bv[i - D_ - 512];
}

__global__ void rope_tab_k(float* __restrict__ cosT, float* __restrict__ sinT) {
  int i = blockIdx.x * 256 + threadIdx.x;  // 2048*32
  int d = i & 31;
  int t = i >> 5;
  float inv = expf(-(float)d * (1.0f / 32.0f) * logf(10000.0f));
  float f = (float)t * inv;
  cosT[i] = cosf(f);
  sinT[i] = sinf(f);
}

// ---------------- GEMM: C[m][n] = sum_k A[m][k]*Bw[n][k] + bias[n] ----------------
// XCD-aware swizzle (T1): contiguous tile chunks per XCD for L2 panel reuse.
#define BM 128
#define BN 128
#define BK 64
__global__ __launch_bounds__(256, 2)
void gemm_bf16(const uint16_t* __restrict__ A, const uint16_t* __restrict__ Bw,
               const float* __restrict__ bias, float* __restrict__ C,
               int M, int N, int K) {
  __shared__ __align__(16) uint16_t As[BM * BK];
  __shared__ __align__(16) uint16_t Bs[BN * BK];
  const int tid = threadIdx.x;
  const int lane = tid & 63;
  const int w = tid >> 6;
  const int wm = w >> 1, wn = w & 1;
  const int l16 = lane & 15, lq = lane >> 4;

  int lin = blockIdx.y * gridDim.x + blockIdx.x;
  int qn = (gridDim.x * gridDim.y) >> 3;   // nwg % 8 == 0 for both calls
  int swz = (lin & 7) * qn + (lin >> 3);
  const int m0 = (swz / gridDim.x) * BM, n0 = (swz % gridDim.x) * BN;

  f32x4 acc[4][4] = {};

  for (int k0 = 0; k0 < K; k0 += BK) {
#pragma unroll
    for (int r = 0; r < 4; ++r) {
      int idx = r * 256 + tid;
      int row = idx >> 3;
      int c8 = (idx & 7) ^ (row & 7);
      gload_lds16(A + (size_t)(m0 + row) * K + k0 + c8 * 8, &As[idx * 8]);
    }
#pragma unroll
    for (int r = 0; r < 4; ++r) {
      int idx = r * 256 + tid;
      int row = idx >> 3;
      int c8 = (idx & 7) ^ (row & 7);
      gload_lds16(Bw + (size_t)(n0 + row) * K + k0 + c8 * 8, &Bs[idx * 8]);
    }
    __syncthreads();
#pragma unroll
    for (int ks = 0; ks < 2; ++ks) {
      bf16x8 av[4], bv[4];
      int k8 = ks * 4 + lq;
#pragma unroll
      for (int mi = 0; mi < 4; ++mi) {
        int row = wm * 64 + mi * 16 + l16;
        av[mi] = *reinterpret_cast<const bf16x8*>(&As[row * BK + ((k8 ^ (row & 7)) * 8)]);
      }
#pragma unroll
      for (int ni = 0; ni < 4; ++ni) {
        int row = wn * 64 + ni * 16 + l16;
        bv[ni] = *reinterpret_cast<const bf16x8*>(&Bs[row * BK + ((k8 ^ (row & 7)) * 8)]);
      }
#pragma unroll
      for (int mi = 0; mi < 4; ++mi)
#pragma unroll
        for (int ni = 0; ni < 4; ++ni)
          acc[mi][ni] = __builtin_amdgcn_mfma_f32_16x16x32_bf16(av[mi], bv[ni], acc[mi][ni], 0, 0, 0);
    }
    __syncthreads();
  }

#pragma unroll
  for (int mi = 0; mi < 4; ++mi) {
    int r0 = m0 + wm * 64 + mi * 16 + lq * 4;
#pragma unroll
    for (int ni = 0; ni < 4; ++ni) {
      int c = n0 + wn * 64 + ni * 16 + l16;
      float bb = bias[c];
#pragma unroll
      for (int rr = 0; rr < 4; ++rr)
        C[(size_t)(r0 + rr) * N + c] = acc[mi][ni][rr] + bb;
    }
  }
}

// ---------------- RoPE on Q,K + pack to FRAGMENT-MAJOR bf16 layouts ----------------
// Fragment-major: each 16x32 MFMA fragment's 64 lanes x 16B stored contiguously
// (1KB/fragment) so the flash kernel's fragment loads are single coalesced
// transactions. Q frag id (per b,h): (tile*2+ks)*2+mf; K frag id (per b,kvh):
// (it*2+ks)*4+nf. Lane = lq*16+l16, element offset = lane*8+e (uint16).
// Q is pre-scaled by 0.125*log2(e) (exp2-domain softmax fold).
__global__ void rope_qk_k(const float* __restrict__ QKV, const float* __restrict__ cosT,
                          const float* __restrict__ sinT, uint16_t* __restrict__ qb,
                          uint16_t* __restrict__ kb) {
  int tid = blockIdx.x * 256 + threadIdx.x;  // B*40*T*32
  int d = tid & 31;                           // rope pair index: (d, d+32)
  int t = (tid >> 5) & (T_ - 1);
  int rest = tid >> 16;
  int hh = rest % 40;
  int b = rest / 40;
  const float PREQ = 0.125f * 1.44269504f;
  float c = cosT[t * 32 + d];
  float s = sinT[t * 32 + d];
  size_t rowoff = (size_t)(b * T_ + t) * NQKV_;
  const int lq = d >> 3, e = d & 7;           // same for d and d+32 (ks differs)
  const int l16 = t & 15;
  const int lofs = (lq * 16 + l16) * 8 + e;
  if (hh < H_) {
    const float* q = QKV + rowoff + hh * 64;
    float x1 = q[d], x2 = q[d + 32];
    int tile = t >> 5, mf = (t >> 4) & 1;
    size_t base = ((size_t)(b * H_ + hh) * 64 + tile) * 2048;
    qb[base + (0 * 2 + mf) * 512 + lofs] = f2bf((x1 * c - x2 * s) * PREQ);  // ks=0
    qb[base + (1 * 2 + mf) * 512 + lofs] = f2bf((x2 * c + x1 * s) * PREQ);  // ks=1
  } else {
    int kh = hh - H_;
    const float* kp = QKV + rowoff + D_ + kh * 64;
    float x1 = kp[d], x2 = kp[d + 32];
    int it = t >> 6, nf = (t >> 4) & 3;
    size_t base = (size_t)(b * KVH_ + kh) * (T_ * HD_) + (size_t)it * 4096;
    kb[base + (0 * 8 + nf) * 512 + lofs] = f2bf(x1 * c - x2 * s);           // ks=0
    kb[base + (4 + nf) * 512 + lofs] = f2bf(x2 * c + x1 * s);               // ks=1
  }
}

// ---------------- V -> fragment-major bf16 (PV A-operand order) ----------------
// V frag id (per b,kvh): (it*2+k2)*4+dn; lane(l16=d&15, lq=(t>>3)&3), e=t&7.
__global__ void cvt_v_k(const float* __restrict__ QKV, uint16_t* __restrict__ vt) {
  int tid = blockIdx.x * 256 + threadIdx.x;
  int t8 = tid & 255;                // t-block of 8: t = t8*8 + i
  int rest = tid >> 8;               // b*512 + kvh*64 + d
  int b = rest >> 9;
  int col = 2560 + (rest & 511);
  int d = rest & 63;
  int kvh = (rest >> 6) & 7;
  uint16_t tmp[8];
#pragma unroll
  for (int i = 0; i < 8; ++i)
    tmp[i] = f2bf(QKV[(size_t)(b * T_ + t8 * 8 + i) * NQKV_ + col]);
  uint4 v;
  v.x = (uint32_t)tmp[0] | ((uint32_t)tmp[1] << 16);
  v.y = (uint32_t)tmp[2] | ((uint32_t)tmp[3] << 16);
  v.z = (uint32_t)tmp[4] | ((uint32_t)tmp[5] << 16);
  v.w = (uint32_t)tmp[6] | ((uint32_t)tmp[7] << 16);
  int it = t8 >> 3, k2 = (t8 >> 2) & 1, lq = t8 & 3;
  int dn = d >> 4, l16 = d & 15;
  size_t base = (size_t)(b * KVH_ + kvh) * (T_ * HD_);
  *reinterpret_cast<uint4*>(vt + base + ((size_t)(it * 2 + k2) * 4 + dn) * 512 +
                            (lq * 16 + l16) * 8) = v;
}

// ---------------- flash attention (causal, GQA), swapped QK^T ----------------
// r10 math/structure (no row-max, l via ones-MFMA, K dbuf); Q/K/V loads are now
// fragment-major -> every fragment load is ONE coalesced 1KB transaction
// (was 16 cache lines each -> 256 L1 split-transactions per iteration).
__global__ __launch_bounds__(256, 2)
void flash_attn_k(const uint16_t* __restrict__ qb, const uint16_t* __restrict__ kb,
                  const uint16_t* __restrict__ vt, uint16_t* __restrict__ ob) {
  __shared__ __align__(16) uint16_t P_lds[4][32 * 72];  // per-wave 32 q x 64+pad
  const int lane = threadIdx.x & 63;
  const int w = threadIdx.x >> 6;
  const int l16 = lane & 15, lq = lane >> 4;
  const int bh = (blockIdx.x & 15) * 4 + w;
  const int rank = blockIdx.x >> 4;              // 0..63
  const int pair = rank & 31;
  const int tile = (rank & 32) ? (63 - pair) : pair;
  const int b = bh >> 5, h = bh & 31;
  const int kvh = h >> 2;
  uint16_t* P = P_lds[w];

  const uint16_t* Qp = qb + ((size_t)(b * H_ + h) * 64 + tile) * 2048;
  const uint16_t* Kp = kb + (size_t)(b * KVH_ + kvh) * (T_ * HD_);
  const uint16_t* Vp = vt + (size_t)(b * KVH_ + kvh) * (T_ * HD_);
  const int lofs = lane * 8;

  const int q0 = tile * 32;
  u32x4 ones_u = {0x3F803F80u, 0x3F803F80u, 0x3F803F80u, 0x3F803F80u};
  bf16x8 ones = __builtin_bit_cast(bf16x8, ones_u);

  // Q fragments (B-operand), pre-scaled; frag (ks*2+mf)
  bf16x8 aq[2][2];
#pragma unroll
  for (int mf = 0; mf < 2; ++mf)
#pragma unroll
    for (int ks = 0; ks < 2; ++ks)
      aq[mf][ks] = *reinterpret_cast<const bf16x8*>(Qp + (ks * 2 + mf) * 512 + lofs);

  f32x4 acc[2][4] = {};        // O^T: [q-tile mf][d-tile dn]; lane: q=l16, d=lq*4+r
  f32x4 acc_l[2] = {};         // l (unnormalized softmax denom), col = q = l16

  const int nt = (tile >> 1) + 1;

  bf16x8 kA[2][4], kB[2][4];
  // prologue: K tile 0 into A (frags (0*2+ks)*4+nf)
#pragma unroll
  for (int ks = 0; ks < 2; ++ks)
#pragma unroll
    for (int nf = 0; nf < 4; ++nf)
      kA[ks][nf] = *reinterpret_cast<const bf16x8*>(Kp + (ks * 4 + nf) * 512 + lofs);

#define FLASH_STEP(KCUR, KNXT, IT)                                                     \
  do {                                                                                 \
    const int kv0 = (IT) * 64;                                                         \
    f32x4 sacc[4][2] = {};                                                             \
    _Pragma("unroll")                                                                  \
    for (int ks = 0; ks < 2; ++ks)                                                     \
      _Pragma("unroll")                                                                \
      for (int nf = 0; nf < 4; ++nf)                                                   \
        _Pragma("unroll")                                                              \
        for (int mf = 0; mf < 2; ++mf)                                                 \
          sacc[nf][mf] = __builtin_amdgcn_mfma_f32_16x16x32_bf16(                      \
              KCUR[ks][nf], aq[mf][ks], sacc[nf][mf], 0, 0, 0);                        \
    const int itn = ((IT) + 1 < nt) ? (IT) + 1 : (IT);                                 \
    _Pragma("unroll")                                                                  \
    for (int ks = 0; ks < 2; ++ks)                                                     \
      _Pragma("unroll")                                                                \
      for (int nf = 0; nf < 4; ++nf)                                                   \
        KNXT[ks][nf] = *reinterpret_cast<const bf16x8*>(                               \
            Kp + ((size_t)(itn * 2 + ks) * 4 + nf) * 512 + lofs);                      \
    bf16x8 vv[2][4];                                                                   \
    _Pragma("unroll")                                                                  \
    for (int k2 = 0; k2 < 2; ++k2)                                                     \
      _Pragma("unroll")                                                                \
      for (int dn = 0; dn < 4; ++dn)                                                   \
        vv[k2][dn] = *reinterpret_cast<const bf16x8*>(                                 \
            Vp + ((size_t)((IT) * 2 + k2) * 4 + dn) * 512 + lofs);                     \
    if ((IT) == nt - 1) {                                                              \
      _Pragma("unroll")                                                                \
      for (int mf = 0; mf < 2; ++mf) {                                                 \
        int qg = q0 + mf * 16 + l16;                                                   \
        _Pragma("unroll")                                                              \
        for (int nf = 0; nf < 4; ++nf)                                                 \
          _Pragma("unroll")                                                            \
          for (int r = 0; r < 4; ++r)                                                  \
            if (kv0 + nf * 16 + lq * 4 + r > qg) sacc[nf][mf][r] = -1e30f;             \
      }                                                                                \
    }                                                                                  \
    _Pragma("unroll")                                                                  \
    for (int mf = 0; mf < 2; ++mf) {                                                   \
      uint16_t* rowp = P + (mf * 16 + l16) * 72;                                       \
      _Pragma("unroll")                                                                \
      for (int nf = 0; nf < 4; ++nf) {                                                 \
        float p0 = __builtin_amdgcn_exp2f(sacc[nf][mf][0]);                            \
        float p1 = __builtin_amdgcn_exp2f(sacc[nf][mf][1]);                            \
        float p2 = __builtin_amdgcn_exp2f(sacc[nf][mf][2]);                            \
        float p3 = __builtin_amdgcn_exp2f(sacc[nf][mf][3]);                            \
        uint2 pk;                                                                      \
        pk.x = cvt_pk(p0, p1);                                                         \
        pk.y = cvt_pk(p2, p3);                                                         \
        *reinterpret_cast<uint2*>(rowp + nf * 16 + lq * 4) = pk;                       \
      }                                                                                \
    }                                                                                  \
    bf16x8 pa[2][2];                                                                   \
    _Pragma("unroll")                                                                  \
    for (int mf = 0; mf < 2; ++mf)                                                     \
      _Pragma("unroll")                                                                \
      for (int k2 = 0; k2 < 2; ++k2)                                                   \
        pa[mf][k2] = *reinterpret_cast<const bf16x8*>(                                 \
            P + (mf * 16 + l16) * 72 + k2 * 32 + lq * 8);                              \
    _Pragma("unroll")                                                                  \
    for (int k2 = 0; k2 < 2; ++k2)                                                     \
      _Pragma("unroll")                                                                \
      for (int mf = 0; mf < 2; ++mf) {                                                 \
        acc_l[mf] = __builtin_amdgcn_mfma_f32_16x16x32_bf16(ones, pa[mf][k2],          \
                                                            acc_l[mf], 0, 0, 0);      \
        _Pragma("unroll")                                                              \
        for (int dn = 0; dn < 4; ++dn)                                                 \
          acc[mf][dn] = __builtin_amdgcn_mfma_f32_16x16x32_bf16(                       \
              vv[k2][dn], pa[mf][k2], acc[mf][dn], 0, 0, 0);                           \
      }                                                                                \
  } while (0)

  {
    int it = 0;
    for (;;) {
      FLASH_STEP(kA, kB, it);
      ++it;
      if (it == nt) break;
      FLASH_STEP(kB, kA, it);
      ++it;
      if (it == nt) break;
    }
  }
#undef FLASH_STEP

  // epilogue: normalize, transpose O^T -> O through LDS, coalesced store
#pragma unroll
  for (int mf = 0; mf < 2; ++mf) {
    float inv = 1.0f / acc_l[mf][0];
    uint16_t* rowp = P + (mf * 16 + l16) * 72;
#pragma unroll
    for (int dn = 0; dn < 4; ++dn) {
      uint2 pk;
      pk.x = cvt_pk(acc[mf][dn][0] * inv, acc[mf][dn][1] * inv);
      pk.y = cvt_pk(acc[mf][dn][2] * inv, acc[mf][dn][3] * inv);
      *reinterpret_cast<uint2*>(rowp + dn * 16 + lq * 4) = pk;
    }
  }
  {
    int orow = lane >> 1, ohalf = (lane & 1) * 32;
    uint16_t* op = ob + (size_t)(b * T_ + q0 + orow) * D_ + h * HD_ + ohalf;
    const uint16_t* lp = P + orow * 72 + ohalf;
#pragma unroll
    for (int j = 0; j < 4; ++j)
      *reinterpret_cast<uint4*>(op + j * 8) = *reinterpret_cast<const uint4*>(lp + j * 8);
  }
}

extern "C" void kernel_launch(void* const* d_in, const int* in_sizes, int n_in,
                              void* d_out, int out_size, void* d_ws, size_t ws_size,
                              hipStream_t stream) {
  const float* x  = (const float*)d_in[0];
  const float* Wq = (const float*)d_in[1];
  const float* bq = (const float*)d_in[2];
  const float* Wk = (const float*)d_in[3];
  const float* bk = (const float*)d_in[4];
  const float* Wv = (const float*)d_in[5];
  const float* bv = (const float*)d_in[6];
  const float* Wo = (const float*)d_in[7];
  const float* bo = (const float*)d_in[8];
  float* out = (float*)d_out;

  char* ws = (char*)d_ws;
  size_t off = 0;
  auto alloc = [&](size_t bytes) {
    void* p = ws + off;
    off += (bytes + 255) & ~(size_t)255;
    return p;
  };
  uint16_t* xb    = (uint16_t*)alloc((size_t)M_ * D_ * 2);
  uint16_t* wqkv  = (uint16_t*)alloc((size_t)NQKV_ * D_ * 2);
  uint16_t* wo_b  = (uint16_t*)alloc((size_t)D_ * D_ * 2);
  float*    bqkv  = (float*)alloc(NQKV_ * 4);
  float*    cosT  = (float*)alloc(T_ * 32 * 4);
  float*    sinT  = (float*)alloc(T_ * 32 * 4);
  uint16_t* q_bf  = (uint16_t*)alloc((size_t)B_ * H_ * T_ * HD_ * 2);
  uint16_t* k_bf  = (uint16_t*)alloc((size_t)B_ * KVH_ * T_ * HD_ * 2);
  uint16_t* vt_bf = (uint16_t*)alloc((size_t)B_ * KVH_ * T_ * HD_ * 2);
  float*    qkvf  = (float*)alloc((size_t)M_ * NQKV_ * 4);
  uint16_t* attn_bf = (uint16_t*)qkvf;  // reuse: QKV fp32 dead after rope/cvt_v

  cvt_bf16_k<<<4096, 256, 0, stream>>>(x, xb, M_ * D_);
  cvt_bf16_k<<<2048, 256, 0, stream>>>(Wq, wqkv, D_ * D_);
  cvt_bf16_k<<<512, 256, 0, stream>>>(Wk, wqkv + (size_t)D_ * D_, 512 * D_);
  cvt_bf16_k<<<512, 256, 0, stream>>>(Wv, wqkv + (size_t)2560 * D_, 512 * D_);
  cvt_bf16_k<<<2048, 256, 0, stream>>>(Wo, wo_b, D_ * D_);
  concat_bias_k<<<12, 256, 0, stream>>>(bq, bk, bv, bqkv);
  rope_tab_k<<<256, 256, 0, stream>>>(cosT, sinT);

  gemm_bf16<<<dim3(NQKV_ / BN, M_ / BM), 256, 0, stream>>>(xb, wqkv, bqkv, qkvf, M_, NQKV_, D_);

  rope_qk_k<<<(B_ * 40 * T_ * 32) / 256, 256, 0, stream>>>(qkvf, cosT, sinT, q_bf, k_bf);
  cvt_v_k<<<(B_ * KVH_ * HD_ * (T_ / 8)) / 256, 256, 0, stream>>>(qkvf, vt_bf);

  flash_attn_k<<<1024, 256, 0, stream>>>(q_bf, k_bf, vt_bf, attn_bf);

  gemm_bf16<<<dim3(D_ / BN, M_ / BM), 256, 0, stream>>>(attn_bf, wo_b, bo, out, M_, D_, D_);
}